// Round 3
// baseline (2230.107 us; speedup 1.0000x reference)
//
#include <hip/hip_runtime.h>

// SolvGNNV6 round 3: bf16 MFMA everywhere (conv BN=256 tile, MLP 128x128),
// MLP-parallel gather (4-wide neighbor batching), fp32 final GEMV.

#define NN 81920     // nodes
#define NE 327680    // edges
#define NB 2048      // graphs
#define H 256
#define INDIM 74
#define KPAD 128     // first-conv K padded 74 -> 128
#define ZK 544       // MLP1 K padded 520 -> 544 (17 * 32)
#define DEGCAP 32    // max in-degree bucket (Poisson(4); P(>32) ~ 1e-19)

typedef unsigned short u16;
typedef __attribute__((ext_vector_type(8))) short short8;  // 8 bf16 (4 VGPRs)
typedef __attribute__((ext_vector_type(4))) float f32x4;

__device__ inline u16 f2b(float f) {  // fp32 -> bf16 bits, RNE
    unsigned u = __builtin_bit_cast(unsigned, f);
    u += 0x7fffu + ((u >> 16) & 1u);
    return (u16)(u >> 16);
}
__device__ inline float b2f(u16 b) {
    unsigned u = ((unsigned)b) << 16;
    return __builtin_bit_cast(float, u);
}
__device__ inline float blo(unsigned u) { return __builtin_bit_cast(float, u << 16); }
__device__ inline float bhi(unsigned u) { return __builtin_bit_cast(float, u & 0xffff0000u); }

// ---------- degree count + bucket fill ----------
__global__ void fill_kernel(const int* __restrict__ src, const int* __restrict__ dst,
                            int* __restrict__ dego, int* __restrict__ cnti,
                            int* __restrict__ bucket) {
    int e = blockIdx.x * 256 + threadIdx.x;
    if (e < NE) {
        int s = src[e], d = dst[e];
        atomicAdd(&dego[s], 1);
        int p = atomicAdd(&cnti[d], 1);
        if (p < DEGCAP) bucket[d * DEGCAP + p] = s;
    }
}

__global__ void rsqrt_kernel(const int* __restrict__ dego, const int* __restrict__ cnti,
                             float* __restrict__ rso, float* __restrict__ rsi) {
    int i = blockIdx.x * 256 + threadIdx.x;
    if (i < NN) {
        rso[i] = rsqrtf((float)(dego[i] > 1 ? dego[i] : 1));
        rsi[i] = rsqrtf((float)(cnti[i] > 1 ? cnti[i] : 1));
    }
}

// ---------- first-conv aggregation: fp32 x (74) -> bf16 agg (pad to 128) ----------
__global__ __launch_bounds__(128) void gather_x_kernel(
        const float* __restrict__ x, const int* __restrict__ bucket,
        const int* __restrict__ cnti, const float* __restrict__ rso,
        const float* __restrict__ rsi, u16* __restrict__ out) {
    int node = blockIdx.x;
    int f = threadIdx.x;
    int deg = cnti[node]; if (deg > DEGCAP) deg = DEGCAP;
    float acc = 0.f;
    if (f < INDIM) {
        for (int j = 0; j < deg; ++j) {
            int sn = bucket[node * DEGCAP + j];
            acc += x[(size_t)sn * INDIM + f] * rso[sn];
        }
    }
    out[(size_t)node * KPAD + f] = f2b(acc * rsi[node]);
}

// ---------- H-dim aggregation, 4-wide neighbor batching for MLP ----------
__global__ __launch_bounds__(256) void gather_h_kernel(
        const u16* __restrict__ h, const int* __restrict__ bucket,
        const int* __restrict__ cnti, const float* __restrict__ rso,
        const float* __restrict__ rsi, u16* __restrict__ out) {
    int node = blockIdx.x * 8 + (threadIdx.x >> 5);
    int fc = (threadIdx.x & 31) * 8;     // 8 bf16 = 16 B per thread
    int deg = cnti[node]; if (deg > DEGCAP) deg = DEGCAP;
    const int* bk = bucket + node * DEGCAP;
    float acc[8] = {};
    for (int base = 0; base < deg; base += 4) {
        // batch 4 indices+weights so the 4 row loads issue concurrently
        int i0 = bk[base];
        int i1 = (base + 1 < deg) ? bk[base + 1] : i0;
        int i2 = (base + 2 < deg) ? bk[base + 2] : i0;
        int i3 = (base + 3 < deg) ? bk[base + 3] : i0;
        float w0 = rso[i0];
        float w1 = (base + 1 < deg) ? rso[i1] : 0.f;
        float w2 = (base + 2 < deg) ? rso[i2] : 0.f;
        float w3 = (base + 3 < deg) ? rso[i3] : 0.f;
        uint4 v0 = *(const uint4*)(h + (size_t)i0 * H + fc);
        uint4 v1 = *(const uint4*)(h + (size_t)i1 * H + fc);
        uint4 v2 = *(const uint4*)(h + (size_t)i2 * H + fc);
        uint4 v3 = *(const uint4*)(h + (size_t)i3 * H + fc);
        acc[0] += blo(v0.x) * w0 + blo(v1.x) * w1 + blo(v2.x) * w2 + blo(v3.x) * w3;
        acc[1] += bhi(v0.x) * w0 + bhi(v1.x) * w1 + bhi(v2.x) * w2 + bhi(v3.x) * w3;
        acc[2] += blo(v0.y) * w0 + blo(v1.y) * w1 + blo(v2.y) * w2 + blo(v3.y) * w3;
        acc[3] += bhi(v0.y) * w0 + bhi(v1.y) * w1 + bhi(v2.y) * w2 + bhi(v3.y) * w3;
        acc[4] += blo(v0.z) * w0 + blo(v1.z) * w1 + blo(v2.z) * w2 + blo(v3.z) * w3;
        acc[5] += bhi(v0.z) * w0 + bhi(v1.z) * w1 + bhi(v2.z) * w2 + bhi(v3.z) * w3;
        acc[6] += blo(v0.w) * w0 + blo(v1.w) * w1 + blo(v2.w) * w2 + blo(v3.w) * w3;
        acc[7] += bhi(v0.w) * w0 + bhi(v1.w) * w1 + bhi(v2.w) * w2 + bhi(v3.w) * w3;
    }
    float ri = rsi[node];
    u16 o[8];
#pragma unroll
    for (int i = 0; i < 8; ++i) o[i] = f2b(acc[i] * ri);
    uint4 ov;
    ov.x = o[0] | ((unsigned)o[1] << 16);
    ov.y = o[2] | ((unsigned)o[3] << 16);
    ov.z = o[4] | ((unsigned)o[5] << 16);
    ov.w = o[6] | ((unsigned)o[7] << 16);
    *(uint4*)(out + (size_t)node * H + fc) = ov;
}

// ---------- weight prep: fp32 row-major -> bf16 transposed (N-major, K-contig) ----------
__global__ void prep_w0_kernel(const float* __restrict__ W0, u16* __restrict__ Wt0) {
    int i = blockIdx.x * 256 + threadIdx.x;  // 256*128
    int n = i >> 7, k = i & 127;
    float v = (k < INDIM) ? W0[(size_t)k * H + n] : 0.f;
    Wt0[i] = f2b(v);
}

__global__ void prep_gcr_kernel(const float* __restrict__ W, u16* __restrict__ Wt) {
    int i = blockIdx.x * 256 + threadIdx.x;  // 65536 per layer
    int l = blockIdx.y;                      // 0..9
    int n = i >> 8, k = i & 255;
    Wt[(size_t)l * 65536 + i] = f2b(W[(size_t)l * 65536 + (size_t)k * H + n]);
}

__global__ void prep_w1_kernel(const float* __restrict__ W, u16* __restrict__ Wt) {
    int i = blockIdx.x * 256 + threadIdx.x;  // 1024 * 544
    if (i >= 1024 * ZK) return;
    int n = i / ZK, k = i - n * ZK;
    float v = (k < 520) ? W[(size_t)k * 1024 + n] : 0.f;
    Wt[i] = f2b(v);
}

__global__ void prep_w2_kernel(const float* __restrict__ W, u16* __restrict__ Wt) {
    int i = blockIdx.x * 256 + threadIdx.x;  // 512 * 1024
    int n = i >> 10, k = i & 1023;
    Wt[i] = f2b(W[(size_t)k * 512 + n]);
}

// ---------- bf16 MFMA GEMM helpers ----------
__device__ inline void ldg_lds16(const u16* g, u16* l) {
    __builtin_amdgcn_global_load_lds(
        (const __attribute__((address_space(1))) unsigned int*)g,
        (__attribute__((address_space(3))) unsigned int*)l, 16, 0, 0);
}
__device__ inline float actf(float v, int act) {
    if (act == 1) return fmaxf(v, 0.f);
    if (act == 2) return (v > 0.f) ? v : 0.01f * v;
    return v;
}

// ---------- conv GEMM: C[M,256] = act(A @ Bt^T + bias), BM=128 BN=256 BK=32 ----------
// A: M x K (lda), Bt: 256 x K (ldb). grid.x = M/128. 4 waves: 2x2 over 128x256.
__global__ __launch_bounds__(256) void gemm_conv_kernel(
        const u16* __restrict__ A, int lda,
        const u16* __restrict__ Bt, int ldb,
        const float* __restrict__ bias, u16* __restrict__ C,
        int Kiters, int act) {
    __shared__ u16 As[4096];   // 128 x 32 bf16, 8 KB
    __shared__ u16 Bs[8192];   // 256 x 32 bf16, 16 KB
    int t = threadIdx.x;
    int wave = t >> 6, lane = t & 63;
    int wr = wave >> 1, wc = wave & 1;   // row-half, col-half
    int row0 = blockIdx.x * 128;

    int r = t >> 2;            // 0..63
    int kq = (t & 3) * 8;      // element offset within BK=32
    const u16* Ag0 = A + (size_t)(row0 + r) * lda + kq;
    const u16* Ag1 = A + (size_t)(row0 + 64 + r) * lda + kq;
    const u16* Bg0 = Bt + (size_t)(r) * ldb + kq;
    const u16* Bg1 = Bt + (size_t)(64 + r) * ldb + kq;
    const u16* Bg2 = Bt + (size_t)(128 + r) * ldb + kq;
    const u16* Bg3 = Bt + (size_t)(192 + r) * ldb + kq;
    u16* AsW = As + wave * 512;
    u16* BsW = Bs + wave * 512;

    f32x4 acc[4][8] = {};
    int mrow = lane & 15;
    int koff = (lane >> 4) * 8;

    for (int kt = 0; kt < Kiters; ++kt) {
        ldg_lds16(Ag0, AsW);
        ldg_lds16(Ag1, AsW + 2048);
        ldg_lds16(Bg0, BsW);
        ldg_lds16(Bg1, BsW + 2048);
        ldg_lds16(Bg2, BsW + 4096);
        ldg_lds16(Bg3, BsW + 6144);
        __syncthreads();
        short8 a[4], b[8];
#pragma unroll
        for (int mt = 0; mt < 4; ++mt)
            a[mt] = *(const short8*)(As + (size_t)(wr * 64 + mt * 16 + mrow) * 32 + koff);
#pragma unroll
        for (int nt = 0; nt < 8; ++nt)
            b[nt] = *(const short8*)(Bs + (size_t)(wc * 128 + nt * 16 + mrow) * 32 + koff);
#pragma unroll
        for (int mt = 0; mt < 4; ++mt)
#pragma unroll
            for (int nt = 0; nt < 8; ++nt)
                acc[mt][nt] = __builtin_amdgcn_mfma_f32_16x16x32_bf16(
                    a[mt], b[nt], acc[mt][nt], 0, 0, 0);
        __syncthreads();
        Ag0 += 32; Ag1 += 32; Bg0 += 32; Bg1 += 32; Bg2 += 32; Bg3 += 32;
    }

#pragma unroll
    for (int mt = 0; mt < 4; ++mt) {
        int rb = row0 + wr * 64 + mt * 16 + (lane >> 4) * 4;
#pragma unroll
        for (int nt = 0; nt < 8; ++nt) {
            int c = wc * 128 + nt * 16 + (lane & 15);
            float bv = bias[c];
#pragma unroll
            for (int q = 0; q < 4; ++q) {
                float v = actf(acc[mt][nt][q] + bv, act);
                C[(size_t)(rb + q) * H + c] = f2b(v);
            }
        }
    }
}

// ---------- generic 128x128 MFMA GEMM (MLP head), param ldc ----------
__global__ __launch_bounds__(256) void gemm_mfma_kernel(
        const u16* __restrict__ A, int lda,
        const u16* __restrict__ Bt, int ldb,
        const float* __restrict__ bias, u16* __restrict__ C, int ldc,
        int Kiters, int act) {
    __shared__ u16 As[4096];
    __shared__ u16 Bs[4096];
    int t = threadIdx.x;
    int wave = t >> 6, lane = t & 63;
    int wr = wave >> 1, wc = wave & 1;
    int row0 = blockIdx.x * 128, col0 = blockIdx.y * 128;

    int r = t >> 2;
    int kq = (t & 3) * 8;
    const u16* Ag0 = A + (size_t)(row0 + r) * lda + kq;
    const u16* Ag1 = A + (size_t)(row0 + 64 + r) * lda + kq;
    const u16* Bg0 = Bt + (size_t)(col0 + r) * ldb + kq;
    const u16* Bg1 = Bt + (size_t)(col0 + 64 + r) * ldb + kq;
    u16* AsW = As + wave * 512;
    u16* BsW = Bs + wave * 512;

    f32x4 acc[4][4] = {};
    int mrow = lane & 15;
    int koff = (lane >> 4) * 8;

    for (int kt = 0; kt < Kiters; ++kt) {
        ldg_lds16(Ag0, AsW);
        ldg_lds16(Ag1, AsW + 2048);
        ldg_lds16(Bg0, BsW);
        ldg_lds16(Bg1, BsW + 2048);
        __syncthreads();
        short8 a[4], b[4];
#pragma unroll
        for (int mt = 0; mt < 4; ++mt)
            a[mt] = *(const short8*)(As + (size_t)(wr * 64 + mt * 16 + mrow) * 32 + koff);
#pragma unroll
        for (int nt = 0; nt < 4; ++nt)
            b[nt] = *(const short8*)(Bs + (size_t)(wc * 64 + nt * 16 + mrow) * 32 + koff);
#pragma unroll
        for (int mt = 0; mt < 4; ++mt)
#pragma unroll
            for (int nt = 0; nt < 4; ++nt)
                acc[mt][nt] = __builtin_amdgcn_mfma_f32_16x16x32_bf16(
                    a[mt], b[nt], acc[mt][nt], 0, 0, 0);
        __syncthreads();
        Ag0 += 32; Ag1 += 32; Bg0 += 32; Bg1 += 32;
    }

#pragma unroll
    for (int mt = 0; mt < 4; ++mt) {
        int rb = row0 + wr * 64 + mt * 16 + (lane >> 4) * 4;
#pragma unroll
        for (int nt = 0; nt < 4; ++nt) {
            int c = col0 + wc * 64 + nt * 16 + (lane & 15);
            float bv = bias[c];
#pragma unroll
            for (int q = 0; q < 4; ++q) {
                float v = actf(acc[mt][nt][q] + bv, act);
                C[(size_t)(rb + q) * ldc + c] = f2b(v);
            }
        }
    }
}

// ---------- pooling: sum 40 bf16 rows -> bf16 z (stride ZK) ----------
__global__ __launch_bounds__(256) void pool_kernel(const u16* __restrict__ h,
                                                   u16* __restrict__ z, int zoff) {
    int g = blockIdx.x, f = threadIdx.x;
    float acc = 0.f;
    const u16* base = h + (size_t)g * 40 * H + f;
#pragma unroll
    for (int j = 0; j < 40; ++j) acc += b2f(base[j * H]);
    z[(size_t)g * ZK + zoff + f] = f2b(acc);
}

__global__ void copy_add_kernel(const float* __restrict__ add, u16* __restrict__ z) {
    int i = blockIdx.x * 256 + threadIdx.x;
    if (i < NB * 8) {
        int g = i >> 3, a = i & 7;
        z[(size_t)g * ZK + 512 + a] = f2b(add[i]);
    }
}

// ---------- final GEMV: out[r] = sum_k m2b[r,k]*w[k] + b ----------
__global__ void gemv_out_kernel(const u16* __restrict__ A, const float* __restrict__ w,
                                const float* __restrict__ b, float* __restrict__ out, int K) {
    int wave = threadIdx.x >> 6;
    int lane = threadIdx.x & 63;
    int row = blockIdx.x * 4 + wave;
    float acc = 0.f;
    for (int k = lane; k < K; k += 64) acc += b2f(A[(size_t)row * K + k]) * w[k];
#pragma unroll
    for (int off = 32; off > 0; off >>= 1) acc += __shfl_down(acc, off, 64);
    if (lane == 0) out[row] = acc + b[0];
}

extern "C" void kernel_launch(void* const* d_in, const int* in_sizes, int n_in,
                              void* d_out, int out_size, void* d_ws, size_t ws_size,
                              hipStream_t stream) {
    const int*   cat_src = (const int*)d_in[0];
    const int*   cat_dst = (const int*)d_in[1];
    const float* cat_x   = (const float*)d_in[3];
    const int*   an_src  = (const int*)d_in[4];
    const int*   an_dst  = (const int*)d_in[5];
    const float* an_x    = (const float*)d_in[7];
    const float* add_f   = (const float*)d_in[8];
    const float* W0      = (const float*)d_in[9];
    const float* b0      = (const float*)d_in[10];
    const float* gcrW    = (const float*)d_in[11];
    const float* gcrb    = (const float*)d_in[12];
    const float* mW1     = (const float*)d_in[13];
    const float* mb1     = (const float*)d_in[14];
    const float* mW2     = (const float*)d_in[15];
    const float* mb2     = (const float*)d_in[16];
    const float* mW3     = (const float*)d_in[17];
    const float* mb3     = (const float*)d_in[18];
    float* out = (float*)d_out;

    // ---- workspace carve (~135 MB) ----
    char* p = (char*)d_ws;
    auto alloc = [&](size_t bytes) -> void* {
        void* rp = (void*)p;
        p += (bytes + 255) & ~(size_t)255;
        return rp;
    };
    int*   dego   = (int*)alloc((size_t)NN * 4);
    int*   cnti   = (int*)alloc((size_t)NN * 4);
    int*   bucket = (int*)alloc((size_t)NN * DEGCAP * 4);
    float* rso    = (float*)alloc((size_t)NN * 4);
    float* rsi    = (float*)alloc((size_t)NN * 4);
    u16*   aggx   = (u16*)alloc((size_t)NN * KPAD * 2);
    u16*   hA     = (u16*)alloc((size_t)NN * H * 2);
    u16*   hB     = (u16*)alloc((size_t)NN * H * 2);
    u16*   Wt0    = (u16*)alloc((size_t)H * KPAD * 2);
    u16*   Wtg    = (u16*)alloc((size_t)10 * H * H * 2);
    u16*   Wt1    = (u16*)alloc((size_t)1024 * ZK * 2);
    u16*   Wt2    = (u16*)alloc((size_t)512 * 1024 * 2);
    u16*   zb     = (u16*)alloc((size_t)NB * ZK * 2);
    u16*   m1b    = (u16*)alloc((size_t)NB * 1024 * 2);
    u16*   m2b    = (u16*)alloc((size_t)NB * 512 * 2);
    (void)ws_size; (void)in_sizes; (void)n_in; (void)out_size;

    // weight prep (bf16 transposed)
    prep_w0_kernel<<<(H * KPAD) / 256, 256, 0, stream>>>(W0, Wt0);
    prep_gcr_kernel<<<dim3(H * H / 256, 10), 256, 0, stream>>>(gcrW, Wtg);
    prep_w1_kernel<<<(1024 * ZK + 255) / 256, 256, 0, stream>>>(mW1, Wt1);
    prep_w2_kernel<<<(512 * 1024) / 256, 256, 0, stream>>>(mW2, Wt2);
    hipMemsetAsync(zb, 0, (size_t)NB * ZK * 2, stream);  // zero K-pad cols

    auto run_side = [&](const int* src, const int* dst, const float* x, int zoff) {
        hipMemsetAsync(dego, 0, (size_t)NN * 4, stream);
        hipMemsetAsync(cnti, 0, (size_t)NN * 4, stream);
        fill_kernel<<<(NE + 255) / 256, 256, 0, stream>>>(src, dst, dego, cnti, bucket);
        rsqrt_kernel<<<NN / 256, 256, 0, stream>>>(dego, cnti, rso, rsi);

        gather_x_kernel<<<NN, 128, 0, stream>>>(x, bucket, cnti, rso, rsi, aggx);
        gemm_conv_kernel<<<NN / 128, 256, 0, stream>>>(aggx, KPAD, Wt0, KPAD, b0, hA,
                                                       KPAD / 32, 0);
        for (int l = 0; l < 10; ++l) {
            gather_h_kernel<<<NN / 8, 256, 0, stream>>>(hA, bucket, cnti, rso, rsi, hB);
            gemm_conv_kernel<<<NN / 128, 256, 0, stream>>>(hB, H, Wtg + (size_t)l * H * H, H,
                                                           gcrb + (size_t)l * H, hA, H / 32, 1);
        }
        pool_kernel<<<NB, 256, 0, stream>>>(hA, zb, zoff);
    };

    run_side(cat_src, cat_dst, cat_x, 0);
    run_side(an_src, an_dst, an_x, H);
    copy_add_kernel<<<(NB * 8 + 255) / 256, 256, 0, stream>>>(add_f, zb);

    // MLP head (bf16 MFMA)
    gemm_mfma_kernel<<<dim3(NB / 128, 1024 / 128), 256, 0, stream>>>(
        zb, ZK, Wt1, ZK, mb1, m1b, 1024, ZK / 32, 2);
    gemm_mfma_kernel<<<dim3(NB / 128, 512 / 128), 256, 0, stream>>>(
        m1b, 1024, Wt2, 1024, mb2, m2b, 512, 1024 / 32, 2);
    gemv_out_kernel<<<NB / 4, 256, 0, stream>>>(m2b, mW3, mb3, out, 512);
}

// Round 4
// 1749.305 us; speedup vs baseline: 1.2749x; 1.2749x over previous
//
#include <hip/hip_runtime.h>

// SolvGNNV6 round 4: round-2 proven conv structure (128x128 MFMA GEMM,
// simple gather_h) + bf16 MLP head (round-3 win) + 4-wide-batched gather_x.

#define NN 81920     // nodes
#define NE 327680    // edges
#define NB 2048      // graphs
#define H 256
#define INDIM 74
#define KPAD 128     // first-conv K padded 74 -> 128
#define ZK 544       // MLP1 K padded 520 -> 544 (17 * 32)
#define DEGCAP 32    // max in-degree bucket (Poisson(4); P(>32) ~ 1e-19)

typedef unsigned short u16;
typedef __attribute__((ext_vector_type(8))) short short8;  // 8 bf16 (4 VGPRs)
typedef __attribute__((ext_vector_type(4))) float f32x4;

__device__ inline u16 f2b(float f) {  // fp32 -> bf16 bits, RNE
    unsigned u = __builtin_bit_cast(unsigned, f);
    u += 0x7fffu + ((u >> 16) & 1u);
    return (u16)(u >> 16);
}
__device__ inline float b2f(u16 b) {
    unsigned u = ((unsigned)b) << 16;
    return __builtin_bit_cast(float, u);
}
__device__ inline float blo(unsigned u) { return __builtin_bit_cast(float, u << 16); }
__device__ inline float bhi(unsigned u) { return __builtin_bit_cast(float, u & 0xffff0000u); }

// ---------- degree count + bucket fill ----------
__global__ void fill_kernel(const int* __restrict__ src, const int* __restrict__ dst,
                            int* __restrict__ dego, int* __restrict__ cnti,
                            int* __restrict__ bucket) {
    int e = blockIdx.x * 256 + threadIdx.x;
    if (e < NE) {
        int s = src[e], d = dst[e];
        atomicAdd(&dego[s], 1);
        int p = atomicAdd(&cnti[d], 1);
        if (p < DEGCAP) bucket[d * DEGCAP + p] = s;
    }
}

__global__ void rsqrt_kernel(const int* __restrict__ dego, const int* __restrict__ cnti,
                             float* __restrict__ rso, float* __restrict__ rsi) {
    int i = blockIdx.x * 256 + threadIdx.x;
    if (i < NN) {
        rso[i] = rsqrtf((float)(dego[i] > 1 ? dego[i] : 1));
        rsi[i] = rsqrtf((float)(cnti[i] > 1 ? cnti[i] : 1));
    }
}

// ---------- first-conv aggregation, 4-wide neighbor batching ----------
__global__ __launch_bounds__(128) void gather_x_kernel(
        const float* __restrict__ x, const int* __restrict__ bucket,
        const int* __restrict__ cnti, const float* __restrict__ rso,
        const float* __restrict__ rsi, u16* __restrict__ out) {
    int node = blockIdx.x;
    int f = threadIdx.x;
    int deg = cnti[node]; if (deg > DEGCAP) deg = DEGCAP;
    const int* bk = bucket + node * DEGCAP;
    float acc = 0.f;
    if (f < INDIM) {
        for (int base = 0; base < deg; base += 4) {
            int i0 = bk[base];
            int i1 = (base + 1 < deg) ? bk[base + 1] : i0;
            int i2 = (base + 2 < deg) ? bk[base + 2] : i0;
            int i3 = (base + 3 < deg) ? bk[base + 3] : i0;
            float w0 = rso[i0];
            float w1 = (base + 1 < deg) ? rso[i1] : 0.f;
            float w2 = (base + 2 < deg) ? rso[i2] : 0.f;
            float w3 = (base + 3 < deg) ? rso[i3] : 0.f;
            float v0 = x[(size_t)i0 * INDIM + f];
            float v1 = x[(size_t)i1 * INDIM + f];
            float v2 = x[(size_t)i2 * INDIM + f];
            float v3 = x[(size_t)i3 * INDIM + f];
            acc += v0 * w0 + v1 * w1 + v2 * w2 + v3 * w3;
        }
    }
    out[(size_t)node * KPAD + f] = f2b(acc * rsi[node]);
}

// ---------- H-dim aggregation (round-2 proven simple loop) ----------
__global__ __launch_bounds__(256) void gather_h_kernel(
        const u16* __restrict__ h, const int* __restrict__ bucket,
        const int* __restrict__ cnti, const float* __restrict__ rso,
        const float* __restrict__ rsi, u16* __restrict__ out) {
    int node = blockIdx.x * 8 + (threadIdx.x >> 5);
    int fc = (threadIdx.x & 31) * 8;     // 8 bf16 = 16 B per thread
    int deg = cnti[node]; if (deg > DEGCAP) deg = DEGCAP;
    float acc[8] = {};
    for (int j = 0; j < deg; ++j) {
        int sn = bucket[node * DEGCAP + j];
        float w = rso[sn];
        uint4 v = *(const uint4*)(h + (size_t)sn * H + fc);
        acc[0] += blo(v.x) * w; acc[1] += bhi(v.x) * w;
        acc[2] += blo(v.y) * w; acc[3] += bhi(v.y) * w;
        acc[4] += blo(v.z) * w; acc[5] += bhi(v.z) * w;
        acc[6] += blo(v.w) * w; acc[7] += bhi(v.w) * w;
    }
    float ri = rsi[node];
    u16 o[8];
#pragma unroll
    for (int i = 0; i < 8; ++i) o[i] = f2b(acc[i] * ri);
    uint4 ov;
    ov.x = o[0] | ((unsigned)o[1] << 16);
    ov.y = o[2] | ((unsigned)o[3] << 16);
    ov.z = o[4] | ((unsigned)o[5] << 16);
    ov.w = o[6] | ((unsigned)o[7] << 16);
    *(uint4*)(out + (size_t)node * H + fc) = ov;
}

// ---------- weight prep: fp32 row-major -> bf16 transposed (N-major, K-contig) ----------
__global__ void prep_w0_kernel(const float* __restrict__ W0, u16* __restrict__ Wt0) {
    int i = blockIdx.x * 256 + threadIdx.x;  // 256*128
    int n = i >> 7, k = i & 127;
    float v = (k < INDIM) ? W0[(size_t)k * H + n] : 0.f;
    Wt0[i] = f2b(v);
}

__global__ void prep_gcr_kernel(const float* __restrict__ W, u16* __restrict__ Wt) {
    int i = blockIdx.x * 256 + threadIdx.x;  // 65536 per layer
    int l = blockIdx.y;                      // 0..9
    int n = i >> 8, k = i & 255;
    Wt[(size_t)l * 65536 + i] = f2b(W[(size_t)l * 65536 + (size_t)k * H + n]);
}

__global__ void prep_w1_kernel(const float* __restrict__ W, u16* __restrict__ Wt) {
    int i = blockIdx.x * 256 + threadIdx.x;  // 1024 * 544
    if (i >= 1024 * ZK) return;
    int n = i / ZK, k = i - n * ZK;
    float v = (k < 520) ? W[(size_t)k * 1024 + n] : 0.f;
    Wt[i] = f2b(v);
}

__global__ void prep_w2_kernel(const float* __restrict__ W, u16* __restrict__ Wt) {
    int i = blockIdx.x * 256 + threadIdx.x;  // 512 * 1024
    int n = i >> 10, k = i & 1023;
    Wt[i] = f2b(W[(size_t)k * 512 + n]);
}

// ---------- bf16 MFMA GEMM helpers ----------
__device__ inline void ldg_lds16(const u16* g, u16* l) {
    __builtin_amdgcn_global_load_lds(
        (const __attribute__((address_space(1))) unsigned int*)g,
        (__attribute__((address_space(3))) unsigned int*)l, 16, 0, 0);
}
__device__ inline float actf(float v, int act) {
    if (act == 1) return fmaxf(v, 0.f);
    if (act == 2) return (v > 0.f) ? v : 0.01f * v;
    return v;
}

// ---------- 128x128 MFMA GEMM: C = act(A @ Bt^T + bias), BK=32 ----------
// A: M x K (lda), Bt: N x K (ldb), C: M x ldc. grid (M/128, N/128).
__global__ __launch_bounds__(256) void gemm_mfma_kernel(
        const u16* __restrict__ A, int lda,
        const u16* __restrict__ Bt, int ldb,
        const float* __restrict__ bias, u16* __restrict__ C, int ldc,
        int Kiters, int act) {
    __shared__ u16 As[4096];   // 128 x 32 bf16, 8 KB
    __shared__ u16 Bs[4096];
    int t = threadIdx.x;
    int wave = t >> 6, lane = t & 63;
    int wr = wave >> 1, wc = wave & 1;
    int row0 = blockIdx.x * 128, col0 = blockIdx.y * 128;

    int r = t >> 2;            // 0..63
    int kq = (t & 3) * 8;      // element offset within BK=32
    const u16* Ag0 = A + (size_t)(row0 + r) * lda + kq;
    const u16* Ag1 = A + (size_t)(row0 + 64 + r) * lda + kq;
    const u16* Bg0 = Bt + (size_t)(col0 + r) * ldb + kq;
    const u16* Bg1 = Bt + (size_t)(col0 + 64 + r) * ldb + kq;
    u16* AsW = As + wave * 512;  // wave-uniform LDS base (HW adds lane*16)
    u16* BsW = Bs + wave * 512;

    f32x4 acc[4][4] = {};
    int mrow = lane & 15;
    int koff = (lane >> 4) * 8;

    for (int kt = 0; kt < Kiters; ++kt) {
        ldg_lds16(Ag0, AsW);
        ldg_lds16(Ag1, AsW + 2048);
        ldg_lds16(Bg0, BsW);
        ldg_lds16(Bg1, BsW + 2048);
        __syncthreads();
        short8 a[4], b[4];
#pragma unroll
        for (int mt = 0; mt < 4; ++mt)
            a[mt] = *(const short8*)(As + (size_t)(wr * 64 + mt * 16 + mrow) * 32 + koff);
#pragma unroll
        for (int nt = 0; nt < 4; ++nt)
            b[nt] = *(const short8*)(Bs + (size_t)(wc * 64 + nt * 16 + mrow) * 32 + koff);
#pragma unroll
        for (int mt = 0; mt < 4; ++mt)
#pragma unroll
            for (int nt = 0; nt < 4; ++nt)
                acc[mt][nt] = __builtin_amdgcn_mfma_f32_16x16x32_bf16(
                    a[mt], b[nt], acc[mt][nt], 0, 0, 0);
        __syncthreads();
        Ag0 += 32; Ag1 += 32; Bg0 += 32; Bg1 += 32;
    }

    // epilogue: C/D layout col=lane&15, row=(lane>>4)*4+reg (m89-verified)
#pragma unroll
    for (int mt = 0; mt < 4; ++mt) {
        int rb = row0 + wr * 64 + mt * 16 + (lane >> 4) * 4;
#pragma unroll
        for (int nt = 0; nt < 4; ++nt) {
            int c = col0 + wc * 64 + nt * 16 + (lane & 15);
            float bv = bias[c];
#pragma unroll
            for (int q = 0; q < 4; ++q) {
                float v = actf(acc[mt][nt][q] + bv, act);
                C[(size_t)(rb + q) * ldc + c] = f2b(v);
            }
        }
    }
}

// ---------- pooling: sum 40 bf16 rows -> bf16 z (stride ZK) ----------
__global__ __launch_bounds__(256) void pool_kernel(const u16* __restrict__ h,
                                                   u16* __restrict__ z, int zoff) {
    int g = blockIdx.x, f = threadIdx.x;
    float acc = 0.f;
    const u16* base = h + (size_t)g * 40 * H + f;
#pragma unroll
    for (int j = 0; j < 40; ++j) acc += b2f(base[j * H]);
    z[(size_t)g * ZK + zoff + f] = f2b(acc);
}

__global__ void copy_add_kernel(const float* __restrict__ add, u16* __restrict__ z) {
    int i = blockIdx.x * 256 + threadIdx.x;
    if (i < NB * 8) {
        int g = i >> 3, a = i & 7;
        z[(size_t)g * ZK + 512 + a] = f2b(add[i]);
    }
}

// ---------- final GEMV: out[r] = sum_k m2b[r,k]*w[k] + b ----------
__global__ void gemv_out_kernel(const u16* __restrict__ A, const float* __restrict__ w,
                                const float* __restrict__ b, float* __restrict__ out, int K) {
    int wave = threadIdx.x >> 6;
    int lane = threadIdx.x & 63;
    int row = blockIdx.x * 4 + wave;
    float acc = 0.f;
    for (int k = lane; k < K; k += 64) acc += b2f(A[(size_t)row * K + k]) * w[k];
#pragma unroll
    for (int off = 32; off > 0; off >>= 1) acc += __shfl_down(acc, off, 64);
    if (lane == 0) out[row] = acc + b[0];
}

extern "C" void kernel_launch(void* const* d_in, const int* in_sizes, int n_in,
                              void* d_out, int out_size, void* d_ws, size_t ws_size,
                              hipStream_t stream) {
    const int*   cat_src = (const int*)d_in[0];
    const int*   cat_dst = (const int*)d_in[1];
    const float* cat_x   = (const float*)d_in[3];
    const int*   an_src  = (const int*)d_in[4];
    const int*   an_dst  = (const int*)d_in[5];
    const float* an_x    = (const float*)d_in[7];
    const float* add_f   = (const float*)d_in[8];
    const float* W0      = (const float*)d_in[9];
    const float* b0      = (const float*)d_in[10];
    const float* gcrW    = (const float*)d_in[11];
    const float* gcrb    = (const float*)d_in[12];
    const float* mW1     = (const float*)d_in[13];
    const float* mb1     = (const float*)d_in[14];
    const float* mW2     = (const float*)d_in[15];
    const float* mb2     = (const float*)d_in[16];
    const float* mW3     = (const float*)d_in[17];
    const float* mb3     = (const float*)d_in[18];
    float* out = (float*)d_out;

    // ---- workspace carve (~135 MB) ----
    char* p = (char*)d_ws;
    auto alloc = [&](size_t bytes) -> void* {
        void* rp = (void*)p;
        p += (bytes + 255) & ~(size_t)255;
        return rp;
    };
    int*   dego   = (int*)alloc((size_t)NN * 4);
    int*   cnti   = (int*)alloc((size_t)NN * 4);
    int*   bucket = (int*)alloc((size_t)NN * DEGCAP * 4);
    float* rso    = (float*)alloc((size_t)NN * 4);
    float* rsi    = (float*)alloc((size_t)NN * 4);
    u16*   aggx   = (u16*)alloc((size_t)NN * KPAD * 2);
    u16*   hA     = (u16*)alloc((size_t)NN * H * 2);
    u16*   hB     = (u16*)alloc((size_t)NN * H * 2);
    u16*   Wt0    = (u16*)alloc((size_t)H * KPAD * 2);
    u16*   Wtg    = (u16*)alloc((size_t)10 * H * H * 2);
    u16*   Wt1    = (u16*)alloc((size_t)1024 * ZK * 2);
    u16*   Wt2    = (u16*)alloc((size_t)512 * 1024 * 2);
    u16*   zb     = (u16*)alloc((size_t)NB * ZK * 2);
    u16*   m1b    = (u16*)alloc((size_t)NB * 1024 * 2);
    u16*   m2b    = (u16*)alloc((size_t)NB * 512 * 2);
    (void)ws_size; (void)in_sizes; (void)n_in; (void)out_size;

    // weight prep (bf16 transposed)
    prep_w0_kernel<<<(H * KPAD) / 256, 256, 0, stream>>>(W0, Wt0);
    prep_gcr_kernel<<<dim3(H * H / 256, 10), 256, 0, stream>>>(gcrW, Wtg);
    prep_w1_kernel<<<(1024 * ZK + 255) / 256, 256, 0, stream>>>(mW1, Wt1);
    prep_w2_kernel<<<(512 * 1024) / 256, 256, 0, stream>>>(mW2, Wt2);
    hipMemsetAsync(zb, 0, (size_t)NB * ZK * 2, stream);  // zero K-pad cols

    dim3 cgrid(NN / 128, H / 128);

    auto run_side = [&](const int* src, const int* dst, const float* x, int zoff) {
        hipMemsetAsync(dego, 0, (size_t)NN * 4, stream);
        hipMemsetAsync(cnti, 0, (size_t)NN * 4, stream);
        fill_kernel<<<(NE + 255) / 256, 256, 0, stream>>>(src, dst, dego, cnti, bucket);
        rsqrt_kernel<<<NN / 256, 256, 0, stream>>>(dego, cnti, rso, rsi);

        gather_x_kernel<<<NN, 128, 0, stream>>>(x, bucket, cnti, rso, rsi, aggx);
        gemm_mfma_kernel<<<cgrid, 256, 0, stream>>>(aggx, KPAD, Wt0, KPAD, b0, hA, H,
                                                    KPAD / 32, 0);
        for (int l = 0; l < 10; ++l) {
            gather_h_kernel<<<NN / 8, 256, 0, stream>>>(hA, bucket, cnti, rso, rsi, hB);
            gemm_mfma_kernel<<<cgrid, 256, 0, stream>>>(hB, H, Wtg + (size_t)l * H * H, H,
                                                        gcrb + (size_t)l * H, hA, H,
                                                        H / 32, 1);
        }
        pool_kernel<<<NB, 256, 0, stream>>>(hA, zb, zoff);
    };

    run_side(cat_src, cat_dst, cat_x, 0);
    run_side(an_src, an_dst, an_x, H);
    copy_add_kernel<<<(NB * 8 + 255) / 256, 256, 0, stream>>>(add_f, zb);

    // MLP head (bf16 MFMA)
    gemm_mfma_kernel<<<dim3(NB / 128, 1024 / 128), 256, 0, stream>>>(
        zb, ZK, Wt1, ZK, mb1, m1b, 1024, ZK / 32, 2);
    gemm_mfma_kernel<<<dim3(NB / 128, 512 / 128), 256, 0, stream>>>(
        m1b, 1024, Wt2, 1024, mb2, m2b, 512, 1024 / 32, 2);
    gemv_out_kernel<<<NB / 4, 256, 0, stream>>>(m2b, mW3, mb3, out, 512);
}

// Round 5
// 1698.122 us; speedup vs baseline: 1.3133x; 1.0301x over previous
//
#include <hip/hip_runtime.h>

// SolvGNNV6 round 5: 4-wide gather_h, prescaled-bf16 x gather, and
// LDS-coalesced GEMM epilogue (dwordx4 C stores instead of scalar u16).

#define NN 81920     // nodes
#define NE 327680    // edges
#define NB 2048      // graphs
#define H 256
#define INDIM 74
#define KPAD 128     // first-conv K padded 74 -> 128
#define ZK 544       // MLP1 K padded 520 -> 544 (17 * 32)
#define DEGCAP 32    // max in-degree bucket (Poisson(4); P(>32) ~ 1e-19)
#define CPITCH 132   // C-tile LDS pitch in u16 (264 B -> bank-conflict-free)

typedef unsigned short u16;
typedef __attribute__((ext_vector_type(8))) short short8;  // 8 bf16 (4 VGPRs)
typedef __attribute__((ext_vector_type(4))) float f32x4;

__device__ inline u16 f2b(float f) {  // fp32 -> bf16 bits, RNE
    unsigned u = __builtin_bit_cast(unsigned, f);
    u += 0x7fffu + ((u >> 16) & 1u);
    return (u16)(u >> 16);
}
__device__ inline float b2f(u16 b) {
    unsigned u = ((unsigned)b) << 16;
    return __builtin_bit_cast(float, u);
}
__device__ inline float blo(unsigned u) { return __builtin_bit_cast(float, u << 16); }
__device__ inline float bhi(unsigned u) { return __builtin_bit_cast(float, u & 0xffff0000u); }

// ---------- degree count + bucket fill ----------
__global__ void fill_kernel(const int* __restrict__ src, const int* __restrict__ dst,
                            int* __restrict__ dego, int* __restrict__ cnti,
                            int* __restrict__ bucket) {
    int e = blockIdx.x * 256 + threadIdx.x;
    if (e < NE) {
        int s = src[e], d = dst[e];
        atomicAdd(&dego[s], 1);
        int p = atomicAdd(&cnti[d], 1);
        if (p < DEGCAP) bucket[d * DEGCAP + p] = s;
    }
}

__global__ void rsqrt_kernel(const int* __restrict__ dego, const int* __restrict__ cnti,
                             float* __restrict__ rso, float* __restrict__ rsi) {
    int i = blockIdx.x * 256 + threadIdx.x;
    if (i < NN) {
        rso[i] = rsqrtf((float)(dego[i] > 1 ? dego[i] : 1));
        rsi[i] = rsqrtf((float)(cnti[i] > 1 ? cnti[i] : 1));
    }
}

// ---------- pre-scale x rows by rso, cast to bf16 (halves gather_x traffic) ----------
__global__ __launch_bounds__(128) void prescale_x_kernel(
        const float* __restrict__ x, const float* __restrict__ rso,
        u16* __restrict__ xb) {
    int node = blockIdx.x;
    int f = threadIdx.x;
    if (f < INDIM) {
        float w = rso[node];
        xb[(size_t)node * INDIM + f] = f2b(x[(size_t)node * INDIM + f] * w);
    }
}

// ---------- first-conv aggregation over prescaled bf16 x ----------
__global__ __launch_bounds__(128) void gather_x_kernel(
        const u16* __restrict__ xb, const int* __restrict__ bucket,
        const int* __restrict__ cnti, const float* __restrict__ rsi,
        u16* __restrict__ out) {
    int node = blockIdx.x;
    int f = threadIdx.x;
    int deg = cnti[node]; if (deg > DEGCAP) deg = DEGCAP;
    const int* bk = bucket + node * DEGCAP;
    float acc = 0.f;
    if (f < INDIM) {
        for (int base = 0; base < deg; base += 4) {
            int i0 = bk[base];
            int i1 = (base + 1 < deg) ? bk[base + 1] : i0;  // dup -> broadcast, free
            int i2 = (base + 2 < deg) ? bk[base + 2] : i0;
            int i3 = (base + 3 < deg) ? bk[base + 3] : i0;
            float m1 = (base + 1 < deg) ? 1.f : 0.f;
            float m2 = (base + 2 < deg) ? 1.f : 0.f;
            float m3 = (base + 3 < deg) ? 1.f : 0.f;
            float v0 = b2f(xb[(size_t)i0 * INDIM + f]);
            float v1 = b2f(xb[(size_t)i1 * INDIM + f]);
            float v2 = b2f(xb[(size_t)i2 * INDIM + f]);
            float v3 = b2f(xb[(size_t)i3 * INDIM + f]);
            acc += v0 + m1 * v1 + m2 * v2 + m3 * v3;
        }
    }
    out[(size_t)node * KPAD + f] = f2b(acc * rsi[node]);
}

// ---------- H-dim aggregation, 4-wide neighbor batching ----------
__global__ __launch_bounds__(256) void gather_h_kernel(
        const u16* __restrict__ h, const int* __restrict__ bucket,
        const int* __restrict__ cnti, const float* __restrict__ rso,
        const float* __restrict__ rsi, u16* __restrict__ out) {
    int node = blockIdx.x * 8 + (threadIdx.x >> 5);
    int fc = (threadIdx.x & 31) * 8;     // 8 bf16 = 16 B per thread
    int deg = cnti[node]; if (deg > DEGCAP) deg = DEGCAP;
    const int* bk = bucket + node * DEGCAP;
    float acc[8] = {};
    for (int base = 0; base < deg; base += 4) {
        int i0 = bk[base];
        int i1 = (base + 1 < deg) ? bk[base + 1] : i0;
        int i2 = (base + 2 < deg) ? bk[base + 2] : i0;
        int i3 = (base + 3 < deg) ? bk[base + 3] : i0;
        float w0 = rso[i0];
        float w1 = (base + 1 < deg) ? rso[i1] : 0.f;
        float w2 = (base + 2 < deg) ? rso[i2] : 0.f;
        float w3 = (base + 3 < deg) ? rso[i3] : 0.f;
        uint4 v0 = *(const uint4*)(h + (size_t)i0 * H + fc);
        uint4 v1 = *(const uint4*)(h + (size_t)i1 * H + fc);
        uint4 v2 = *(const uint4*)(h + (size_t)i2 * H + fc);
        uint4 v3 = *(const uint4*)(h + (size_t)i3 * H + fc);
        acc[0] += blo(v0.x) * w0 + blo(v1.x) * w1 + blo(v2.x) * w2 + blo(v3.x) * w3;
        acc[1] += bhi(v0.x) * w0 + bhi(v1.x) * w1 + bhi(v2.x) * w2 + bhi(v3.x) * w3;
        acc[2] += blo(v0.y) * w0 + blo(v1.y) * w1 + blo(v2.y) * w2 + blo(v3.y) * w3;
        acc[3] += bhi(v0.y) * w0 + bhi(v1.y) * w1 + bhi(v2.y) * w2 + bhi(v3.y) * w3;
        acc[4] += blo(v0.z) * w0 + blo(v1.z) * w1 + blo(v2.z) * w2 + blo(v3.z) * w3;
        acc[5] += bhi(v0.z) * w0 + bhi(v1.z) * w1 + bhi(v2.z) * w2 + bhi(v3.z) * w3;
        acc[6] += blo(v0.w) * w0 + blo(v1.w) * w1 + blo(v2.w) * w2 + blo(v3.w) * w3;
        acc[7] += bhi(v0.w) * w0 + bhi(v1.w) * w1 + bhi(v2.w) * w2 + bhi(v3.w) * w3;
    }
    float ri = rsi[node];
    u16 o[8];
#pragma unroll
    for (int i = 0; i < 8; ++i) o[i] = f2b(acc[i] * ri);
    uint4 ov;
    ov.x = o[0] | ((unsigned)o[1] << 16);
    ov.y = o[2] | ((unsigned)o[3] << 16);
    ov.z = o[4] | ((unsigned)o[5] << 16);
    ov.w = o[6] | ((unsigned)o[7] << 16);
    *(uint4*)(out + (size_t)node * H + fc) = ov;
}

// ---------- weight prep: fp32 row-major -> bf16 transposed (N-major, K-contig) ----------
__global__ void prep_w0_kernel(const float* __restrict__ W0, u16* __restrict__ Wt0) {
    int i = blockIdx.x * 256 + threadIdx.x;  // 256*128
    int n = i >> 7, k = i & 127;
    float v = (k < INDIM) ? W0[(size_t)k * H + n] : 0.f;
    Wt0[i] = f2b(v);
}

__global__ void prep_gcr_kernel(const float* __restrict__ W, u16* __restrict__ Wt) {
    int i = blockIdx.x * 256 + threadIdx.x;  // 65536 per layer
    int l = blockIdx.y;                      // 0..9
    int n = i >> 8, k = i & 255;
    Wt[(size_t)l * 65536 + i] = f2b(W[(size_t)l * 65536 + (size_t)k * H + n]);
}

__global__ void prep_w1_kernel(const float* __restrict__ W, u16* __restrict__ Wt) {
    int i = blockIdx.x * 256 + threadIdx.x;  // 1024 * 544
    if (i >= 1024 * ZK) return;
    int n = i / ZK, k = i - n * ZK;
    float v = (k < 520) ? W[(size_t)k * 1024 + n] : 0.f;
    Wt[i] = f2b(v);
}

__global__ void prep_w2_kernel(const float* __restrict__ W, u16* __restrict__ Wt) {
    int i = blockIdx.x * 256 + threadIdx.x;  // 512 * 1024
    int n = i >> 10, k = i & 1023;
    Wt[i] = f2b(W[(size_t)k * 512 + n]);
}

// ---------- bf16 MFMA GEMM helpers ----------
__device__ inline void ldg_lds16(const u16* g, u16* l) {
    __builtin_amdgcn_global_load_lds(
        (const __attribute__((address_space(1))) unsigned int*)g,
        (__attribute__((address_space(3))) unsigned int*)l, 16, 0, 0);
}
__device__ inline float actf(float v, int act) {
    if (act == 1) return fmaxf(v, 0.f);
    if (act == 2) return (v > 0.f) ? v : 0.01f * v;
    return v;
}

// ---------- 128x128 MFMA GEMM: C = act(A @ Bt^T + bias), BK=32 ----------
// A: M x K (lda), Bt: N x K (ldb), C: M x ldc. grid (M/128, N/128).
// Epilogue stages C tile in LDS (padded pitch) -> dwordx4 coalesced stores.
__global__ __launch_bounds__(256) void gemm_mfma_kernel(
        const u16* __restrict__ A, int lda,
        const u16* __restrict__ Bt, int ldb,
        const float* __restrict__ bias, u16* __restrict__ C, int ldc,
        int Kiters, int act) {
    __shared__ __align__(16) u16 smem[128 * CPITCH];  // 33 KB; overlays As/Bs
    u16* As = smem;          // 128 x 32 bf16, 8 KB
    u16* Bs = smem + 4096;   // 128 x 32 bf16, 8 KB
    int t = threadIdx.x;
    int wave = t >> 6, lane = t & 63;
    int wr = wave >> 1, wc = wave & 1;
    int row0 = blockIdx.x * 128, col0 = blockIdx.y * 128;

    int r = t >> 2;            // 0..63
    int kq = (t & 3) * 8;      // element offset within BK=32
    const u16* Ag0 = A + (size_t)(row0 + r) * lda + kq;
    const u16* Ag1 = A + (size_t)(row0 + 64 + r) * lda + kq;
    const u16* Bg0 = Bt + (size_t)(col0 + r) * ldb + kq;
    const u16* Bg1 = Bt + (size_t)(col0 + 64 + r) * ldb + kq;
    u16* AsW = As + wave * 512;  // wave-uniform LDS base (HW adds lane*16)
    u16* BsW = Bs + wave * 512;

    f32x4 acc[4][4] = {};
    int mrow = lane & 15;
    int koff = (lane >> 4) * 8;

    for (int kt = 0; kt < Kiters; ++kt) {
        ldg_lds16(Ag0, AsW);
        ldg_lds16(Ag1, AsW + 2048);
        ldg_lds16(Bg0, BsW);
        ldg_lds16(Bg1, BsW + 2048);
        __syncthreads();
        short8 a[4], b[4];
#pragma unroll
        for (int mt = 0; mt < 4; ++mt)
            a[mt] = *(const short8*)(As + (size_t)(wr * 64 + mt * 16 + mrow) * 32 + koff);
#pragma unroll
        for (int nt = 0; nt < 4; ++nt)
            b[nt] = *(const short8*)(Bs + (size_t)(wc * 64 + nt * 16 + mrow) * 32 + koff);
#pragma unroll
        for (int mt = 0; mt < 4; ++mt)
#pragma unroll
            for (int nt = 0; nt < 4; ++nt)
                acc[mt][nt] = __builtin_amdgcn_mfma_f32_16x16x32_bf16(
                    a[mt], b[nt], acc[mt][nt], 0, 0, 0);
        __syncthreads();   // after this barrier As/Bs of this iter are dead
        Ag0 += 32; Ag1 += 32; Bg0 += 32; Bg1 += 32;
    }

    // ---- epilogue: acc -> LDS (bf16, padded pitch) -> coalesced dwordx4 stores
    // C/D layout: col=lane&15, row=(lane>>4)*4+reg (m89-verified)
#pragma unroll
    for (int mt = 0; mt < 4; ++mt) {
        int rl = wr * 64 + mt * 16 + (lane >> 4) * 4;   // local row base
#pragma unroll
        for (int nt = 0; nt < 4; ++nt) {
            int cl = wc * 64 + nt * 16 + (lane & 15);   // local col
            float bv = bias[col0 + cl];
#pragma unroll
            for (int q = 0; q < 4; ++q) {
                float v = actf(acc[mt][nt][q] + bv, act);
                smem[(size_t)(rl + q) * CPITCH + cl] = f2b(v);
            }
        }
    }
    __syncthreads();
    int rr = t >> 4;       // 0..15
    int seg = t & 15;      // 16 B segment within a 128-col row
#pragma unroll
    for (int pass = 0; pass < 8; ++pass) {
        int row = pass * 16 + rr;
        uint4 val = *(const uint4*)(smem + (size_t)row * CPITCH + seg * 8);
        *(uint4*)(C + (size_t)(row0 + row) * ldc + col0 + seg * 8) = val;
    }
}

// ---------- pooling: sum 40 bf16 rows -> bf16 z (stride ZK) ----------
__global__ __launch_bounds__(256) void pool_kernel(const u16* __restrict__ h,
                                                   u16* __restrict__ z, int zoff) {
    int g = blockIdx.x, f = threadIdx.x;
    float acc = 0.f;
    const u16* base = h + (size_t)g * 40 * H + f;
#pragma unroll
    for (int j = 0; j < 40; ++j) acc += b2f(base[j * H]);
    z[(size_t)g * ZK + zoff + f] = f2b(acc);
}

__global__ void copy_add_kernel(const float* __restrict__ add, u16* __restrict__ z) {
    int i = blockIdx.x * 256 + threadIdx.x;
    if (i < NB * 8) {
        int g = i >> 3, a = i & 7;
        z[(size_t)g * ZK + 512 + a] = f2b(add[i]);
    }
}

// ---------- final GEMV: out[r] = sum_k m2b[r,k]*w[k] + b ----------
__global__ void gemv_out_kernel(const u16* __restrict__ A, const float* __restrict__ w,
                                const float* __restrict__ b, float* __restrict__ out, int K) {
    int wave = threadIdx.x >> 6;
    int lane = threadIdx.x & 63;
    int row = blockIdx.x * 4 + wave;
    float acc = 0.f;
    for (int k = lane; k < K; k += 64) acc += b2f(A[(size_t)row * K + k]) * w[k];
#pragma unroll
    for (int off = 32; off > 0; off >>= 1) acc += __shfl_down(acc, off, 64);
    if (lane == 0) out[row] = acc + b[0];
}

extern "C" void kernel_launch(void* const* d_in, const int* in_sizes, int n_in,
                              void* d_out, int out_size, void* d_ws, size_t ws_size,
                              hipStream_t stream) {
    const int*   cat_src = (const int*)d_in[0];
    const int*   cat_dst = (const int*)d_in[1];
    const float* cat_x   = (const float*)d_in[3];
    const int*   an_src  = (const int*)d_in[4];
    const int*   an_dst  = (const int*)d_in[5];
    const float* an_x    = (const float*)d_in[7];
    const float* add_f   = (const float*)d_in[8];
    const float* W0      = (const float*)d_in[9];
    const float* b0      = (const float*)d_in[10];
    const float* gcrW    = (const float*)d_in[11];
    const float* gcrb    = (const float*)d_in[12];
    const float* mW1     = (const float*)d_in[13];
    const float* mb1     = (const float*)d_in[14];
    const float* mW2     = (const float*)d_in[15];
    const float* mb2     = (const float*)d_in[16];
    const float* mW3     = (const float*)d_in[17];
    const float* mb3     = (const float*)d_in[18];
    float* out = (float*)d_out;

    // ---- workspace carve (~150 MB) ----
    char* p = (char*)d_ws;
    auto alloc = [&](size_t bytes) -> void* {
        void* rp = (void*)p;
        p += (bytes + 255) & ~(size_t)255;
        return rp;
    };
    int*   dego   = (int*)alloc((size_t)NN * 4);
    int*   cnti   = (int*)alloc((size_t)NN * 4);
    int*   bucket = (int*)alloc((size_t)NN * DEGCAP * 4);
    float* rso    = (float*)alloc((size_t)NN * 4);
    float* rsi    = (float*)alloc((size_t)NN * 4);
    u16*   xb     = (u16*)alloc((size_t)NN * INDIM * 2);
    u16*   aggx   = (u16*)alloc((size_t)NN * KPAD * 2);
    u16*   hA     = (u16*)alloc((size_t)NN * H * 2);
    u16*   hB     = (u16*)alloc((size_t)NN * H * 2);
    u16*   Wt0    = (u16*)alloc((size_t)H * KPAD * 2);
    u16*   Wtg    = (u16*)alloc((size_t)10 * H * H * 2);
    u16*   Wt1    = (u16*)alloc((size_t)1024 * ZK * 2);
    u16*   Wt2    = (u16*)alloc((size_t)512 * 1024 * 2);
    u16*   zb     = (u16*)alloc((size_t)NB * ZK * 2);
    u16*   m1b    = (u16*)alloc((size_t)NB * 1024 * 2);
    u16*   m2b    = (u16*)alloc((size_t)NB * 512 * 2);
    (void)ws_size; (void)in_sizes; (void)n_in; (void)out_size;

    // weight prep (bf16 transposed)
    prep_w0_kernel<<<(H * KPAD) / 256, 256, 0, stream>>>(W0, Wt0);
    prep_gcr_kernel<<<dim3(H * H / 256, 10), 256, 0, stream>>>(gcrW, Wtg);
    prep_w1_kernel<<<(1024 * ZK + 255) / 256, 256, 0, stream>>>(mW1, Wt1);
    prep_w2_kernel<<<(512 * 1024) / 256, 256, 0, stream>>>(mW2, Wt2);
    hipMemsetAsync(zb, 0, (size_t)NB * ZK * 2, stream);  // zero K-pad cols

    dim3 cgrid(NN / 128, H / 128);

    auto run_side = [&](const int* src, const int* dst, const float* x, int zoff) {
        hipMemsetAsync(dego, 0, (size_t)NN * 4, stream);
        hipMemsetAsync(cnti, 0, (size_t)NN * 4, stream);
        fill_kernel<<<(NE + 255) / 256, 256, 0, stream>>>(src, dst, dego, cnti, bucket);
        rsqrt_kernel<<<NN / 256, 256, 0, stream>>>(dego, cnti, rso, rsi);

        prescale_x_kernel<<<NN, 128, 0, stream>>>(x, rso, xb);
        gather_x_kernel<<<NN, 128, 0, stream>>>(xb, bucket, cnti, rsi, aggx);
        gemm_mfma_kernel<<<cgrid, 256, 0, stream>>>(aggx, KPAD, Wt0, KPAD, b0, hA, H,
                                                    KPAD / 32, 0);
        for (int l = 0; l < 10; ++l) {
            gather_h_kernel<<<NN / 8, 256, 0, stream>>>(hA, bucket, cnti, rso, rsi, hB);
            gemm_mfma_kernel<<<cgrid, 256, 0, stream>>>(hB, H, Wtg + (size_t)l * H * H, H,
                                                        gcrb + (size_t)l * H, hA, H,
                                                        H / 32, 1);
        }
        pool_kernel<<<NB, 256, 0, stream>>>(hA, zb, zoff);
    };

    run_side(cat_src, cat_dst, cat_x, 0);
    run_side(an_src, an_dst, an_x, H);
    copy_add_kernel<<<(NB * 8 + 255) / 256, 256, 0, stream>>>(add_f, zb);

    // MLP head (bf16 MFMA)
    gemm_mfma_kernel<<<dim3(NB / 128, 1024 / 128), 256, 0, stream>>>(
        zb, ZK, Wt1, ZK, mb1, m1b, 1024, ZK / 32, 2);
    gemm_mfma_kernel<<<dim3(NB / 128, 512 / 128), 256, 0, stream>>>(
        m1b, 1024, Wt2, 1024, mb2, m2b, 512, 1024 / 32, 2);
    gemv_out_kernel<<<NB / 4, 256, 0, stream>>>(m2b, mW3, mb3, out, 512);
}